// Round 6
// baseline (481.536 us; speedup 1.0000x reference)
//
#include <hip/hip_runtime.h>
#include <hip/hip_bf16.h>
#include <math.h>

#define BB 32
#define SS 4096
#define DMEM 512
#define DATT 512

typedef short short8 __attribute__((ext_vector_type(8)));
typedef float floatx4 __attribute__((ext_vector_type(4)));

__device__ inline short f2bf(float x) {
    unsigned u = __float_as_uint(x);
    unsigned r = (u + 0x7fffu + ((u >> 16) & 1u)) >> 16;
    return (short)(r & 0xffffu);
}

// tanh via exp + hardware rcp (v_rcp_f32, ~1ulp): avoids the ~10-instr IEEE
// fdiv expansion. 67M calls per launch -> real VALU savings (R5: VALUBusy 24%).
__device__ inline float fast_tanh(float x) {
    float e = __expf(2.0f * x);
    float r = __builtin_amdgcn_rcpf(e + 1.0f);
    return __builtin_fmaf(-2.0f, r, 1.0f);
}

// async 16B global->LDS DMA; lds base wave-uniform, HW adds lane*16.
__device__ inline void gld_lds16(const void* g, void* l) {
    __builtin_amdgcn_global_load_lds(
        (const __attribute__((address_space(1))) unsigned int*)g,
        (__attribute__((address_space(3))) unsigned int*)l, 16, 0, 0);
}

// ---------------- prep kernels (unchanged, proven) ----------------

__global__ void prep_wt_kernel(const float* __restrict__ Wm, short* __restrict__ Wt) {
    const int n0 = blockIdx.x * 32;
    const int k0 = blockIdx.y * 32;
    const int t = threadIdx.x;
    const int r = t >> 5, c = t & 31;
    __shared__ float lds[32 * 33];
#pragma unroll
    for (int j = 0; j < 4; ++j) {
        int kk = r + j * 8;
        lds[kk * 33 + c] = Wm[(size_t)(k0 + kk) * 512 + n0 + c];
    }
    __syncthreads();
#pragma unroll
    for (int j = 0; j < 4; ++j) {
        int nn = r + j * 8;
        Wt[(size_t)(n0 + nn) * 512 + k0 + c] = f2bf(lds[c * 33 + nn]);
    }
}

__global__ void prep_h_kernel(const float* __restrict__ hidden, const float* __restrict__ Wh,
                              float* __restrict__ h) {
    const int b = blockIdx.x;
    const int n = blockIdx.y * 256 + threadIdx.x;
    const int kc = blockIdx.z;
    float acc = 0.f;
#pragma unroll 8
    for (int k = kc * 128; k < kc * 128 + 128; ++k)
        acc += hidden[b * 512 + k] * Wh[(size_t)k * 512 + n];
    atomicAdd(&h[b * 512 + n], acc);
}

// ---------------- fused score + partial softmax + context (split-S flash) ----------
// R5 post-mortem: 148KB LDS -> 1 block/CU -> Occupancy 22.8%, all pipes <25% busy,
// phases fully serialized. R6: BK 64->32 (16 kt steps): B dbuf 64KB + A 8KB + misc
// -> 76KB LDS -> 2 blocks/CU (16 waves). Two desync'd blocks overlap phases.
// A tile [128 rows][64B], chunk swizzle q ^ ((row>>1)&3): frag ds_read_b128 lands
// 2 lanes/bank-slot (free, m136); staging 8B writes cover all 32 banks per wave.
// B tile [512 rows][64B], DMA-linear LDS + global-side pre-swizzle with the SAME
// (row>>1)&3 involution, so frag reads use one shared address formula.
// Pipeline per kt (full-drain __syncthreads, proven-safe): issue A(kt+1)->regs +
// B(kt+1) DMA -> compute(kt) covers latency -> sync -> write A(kt+1) -> sync.

__global__ __launch_bounds__(512, 2)
void fused_kernel(const float* __restrict__ memory,
                  const float* __restrict__ coverage,
                  const unsigned char* __restrict__ pad,
                  const short* __restrict__ Wt,
                  const float* __restrict__ h,
                  const float* __restrict__ Wc,
                  const float* __restrict__ v,
                  float* __restrict__ pOut,     // = attn output buffer (unnormalized p)
                  float* __restrict__ mWS,
                  float* __restrict__ lWS,
                  float* __restrict__ ctxPart) {
    const int blk = blockIdx.x;
    const int b = blk >> 5;
    const int st = blk & 31;
    const int s0 = st * 128;

    const int tid = threadIdx.x;
    const int lane = tid & 63;
    const int wave = tid >> 6;     // 0..7
    const int wm = wave & 1;       // 2-way m split
    const int wn = wave >> 1;      // 4-way n split
    const int col = lane & 15;
    const int q = lane >> 4;

    // LDS map (total 77824 B = 76 KB -> 2 blocks/CU):
    //   [0,32768)      tileB0   512 rows x 64B (bf16, BK=32)
    //   [32768,65536)  tileB1
    //   [65536,73728)  tileA    128 rows x 64B
    //   [73728,...)    covS 512 | sred 2048 | scoreS 512 | pS 512 | mlS 8
    __shared__ __align__(16) char smem[77824];
    char* tileB0 = smem;
    char* tileB1 = smem + 32768;
    char* tileA  = smem + 65536;
    float* covS   = (float*)(smem + 73728);
    float* sred   = (float*)(smem + 74240);   // [4][128]
    float* scoreS = (float*)(smem + 76288);
    float* pS     = (float*)(smem + 76800);
    float* mlS    = (float*)(smem + 77312);
    float4* red4  = (float4*)smem;            // PV reduce, aliases tileB0 (8KB)

    if (tid < 128) covS[tid] = coverage[(size_t)b * SS + s0 + tid];

    const float4* gA4 = (const float4*)(memory + ((size_t)b * SS + s0) * 512);  // row=128 f4
    const char* gB = (const char*)Wt;         // row pitch 1024B, 512 rows

    // A staging geometry (BK=32): 128 rows x 8 lane-slots of 16B fp32; 1024 slots,
    // 2 per thread. slot s: row=s>>3, l8=s&7; global f4 idx = row*128 + kt*8 + l8;
    // bf16 write: chunk (l8>>1)^((row>>1)&3), byte +(l8&1)*8.
    float4 apf[2];

    floatx4 acc[4][8];
#pragma unroll
    for (int mi = 0; mi < 4; ++mi)
#pragma unroll
        for (int ni = 0; ni < 8; ++ni)
            acc[mi][ni] = (floatx4){0.f, 0.f, 0.f, 0.f};

    // ---- prologue: stage tile 0 ----
#pragma unroll
    for (int j = 0; j < 2; ++j) {
        int s = j * 512 + tid;
        apf[j] = gA4[(size_t)(s >> 3) * 128 + (s & 7)];
    }
#pragma unroll
    for (int it = 0; it < 4; ++it) {
        // B chunk slots ci = it*512 + tid; row = ci>>2, slot = ci&3;
        // LDS slot holds global chunk slot^((row>>1)&3).
        int ci = it * 512 + tid;
        int row = ci >> 2;
        int gch = (ci & 3) ^ ((row >> 1) & 3);
        gld_lds16(gB + (size_t)row * 1024 + gch * 16,
                  tileB0 + it * 8192 + wave * 1024);
    }
#pragma unroll
    for (int j = 0; j < 2; ++j) {
        int s = j * 512 + tid;
        int row = s >> 3, l8 = s & 7;
        union { __hip_bfloat162 h2; unsigned u; } p0, p1;
        p0.h2 = __float22bfloat162_rn(make_float2(apf[j].x, apf[j].y));
        p1.h2 = __float22bfloat162_rn(make_float2(apf[j].z, apf[j].w));
        uint2 w; w.x = p0.u; w.y = p1.u;
        int off = row * 64 + (((l8 >> 1) ^ ((row >> 1) & 3)) << 4) + ((l8 & 1) << 3);
        *(uint2*)(tileA + off) = w;
    }
    __syncthreads();   // drains B DMA + A writes; tile 0 ready

    for (int kt = 0; kt < 16; ++kt) {
        // ---- issue next-tile loads BEFORE compute ----
        if (kt < 15) {
#pragma unroll
            for (int j = 0; j < 2; ++j) {
                int s = j * 512 + tid;
                apf[j] = gA4[(size_t)(s >> 3) * 128 + (kt + 1) * 8 + (s & 7)];
            }
            char* ldsB = ((kt + 1) & 1) ? tileB1 : tileB0;
#pragma unroll
            for (int it = 0; it < 4; ++it) {
                int ci = it * 512 + tid;
                int row = ci >> 2;
                int gch = (ci & 3) ^ ((row >> 1) & 3);
                gld_lds16(gB + (size_t)row * 1024 + (kt + 1) * 64 + gch * 16,
                          ldsB + it * 8192 + wave * 1024);
            }
        }

        // ---- compute tile kt (32 MFMA/wave) ----
        const char* bbase = (kt & 1) ? tileB1 : tileB0;
        short8 af[4], bf[8];
#pragma unroll
        for (int mi = 0; mi < 4; ++mi) {
            int row = wm * 64 + mi * 16 + col;
            af[mi] = *(const short8*)(tileA + row * 64 + ((q ^ ((row >> 1) & 3)) << 4));
        }
#pragma unroll
        for (int ni = 0; ni < 8; ++ni) {
            int row = wn * 128 + ni * 16 + col;
            bf[ni] = *(const short8*)(bbase + row * 64 + ((q ^ ((row >> 1) & 3)) << 4));
        }
#pragma unroll
        for (int mi = 0; mi < 4; ++mi)
#pragma unroll
            for (int ni = 0; ni < 8; ++ni)
                acc[mi][ni] = __builtin_amdgcn_mfma_f32_16x16x32_bf16(af[mi], bf[ni], acc[mi][ni], 0, 0, 0);

        __syncthreads();   // tileA/tileB(kt) reads done; B DMA(kt+1) drained (covered)

        if (kt < 15) {
#pragma unroll
            for (int j = 0; j < 2; ++j) {
                int s = j * 512 + tid;
                int row = s >> 3, l8 = s & 7;
                union { __hip_bfloat162 h2; unsigned u; } p0, p1;
                p0.h2 = __float22bfloat162_rn(make_float2(apf[j].x, apf[j].y));
                p1.h2 = __float22bfloat162_rn(make_float2(apf[j].z, apf[j].w));
                uint2 w; w.x = p0.u; w.y = p1.u;
                int off = row * 64 + (((l8 >> 1) ^ ((row >> 1) & 3)) << 4) + ((l8 & 1) << 3);
                *(uint2*)(tileA + off) = w;
            }
            __syncthreads();   // tile kt+1 (A) visible
        }
    }

    // ---- epilogue: tile scores = sum_n tanh(acc + h + cov*Wc) * v ----
    float hv[8], wcv[8], vv[8];
#pragma unroll
    for (int ni = 0; ni < 8; ++ni) {
        int n = wn * 128 + ni * 16 + col;
        hv[ni] = h[b * 512 + n];
        wcv[ni] = Wc[n];
        vv[ni] = v[n];
    }
    float rowAcc[4][4];
#pragma unroll
    for (int mi = 0; mi < 4; ++mi)
#pragma unroll
        for (int r = 0; r < 4; ++r)
            rowAcc[mi][r] = 0.f;
#pragma unroll
    for (int mi = 0; mi < 4; ++mi) {
#pragma unroll
        for (int r = 0; r < 4; ++r) {
            float cv = covS[wm * 64 + mi * 16 + q * 4 + r];
#pragma unroll
            for (int ni = 0; ni < 8; ++ni) {
                float val = acc[mi][ni][r] + hv[ni] + cv * wcv[ni];
                rowAcc[mi][r] += fast_tanh(val) * vv[ni];
            }
        }
    }
#pragma unroll
    for (int off = 1; off < 16; off <<= 1)
#pragma unroll
        for (int mi = 0; mi < 4; ++mi)
#pragma unroll
            for (int r = 0; r < 4; ++r)
                rowAcc[mi][r] += __shfl_xor(rowAcc[mi][r], off, 64);

    if (col == 0) {
#pragma unroll
        for (int mi = 0; mi < 4; ++mi)
#pragma unroll
            for (int r = 0; r < 4; ++r)
                sred[wn * 128 + wm * 64 + mi * 16 + q * 4 + r] = rowAcc[mi][r];
    }
    __syncthreads();

    // ---- tile softmax (m, p, l) ----
    if (tid < 128) {
        float sc = sred[tid] + sred[128 + tid] + sred[256 + tid] + sred[384 + tid];
        if (pad[(size_t)b * SS + s0 + tid]) sc = -INFINITY;
        scoreS[tid] = sc;
    }
    __syncthreads();
    if (tid < 64) {
        float mx = fmaxf(scoreS[tid], scoreS[tid + 64]);
#pragma unroll
        for (int off = 32; off >= 1; off >>= 1) mx = fmaxf(mx, __shfl_xor(mx, off, 64));
        if (tid == 0) mlS[0] = mx;
    }
    __syncthreads();
    const float mtile = mlS[0];
    if (tid < 128) pS[tid] = __expf(scoreS[tid] - mtile);
    __syncthreads();
    if (tid < 64) {
        float sm = pS[tid] + pS[tid + 64];
#pragma unroll
        for (int off = 32; off >= 1; off >>= 1) sm += __shfl_xor(sm, off, 64);
        if (tid == 0) mlS[1] = sm;
    }
    __syncthreads();

    if (tid < 128) pOut[(size_t)b * SS + s0 + tid] = pS[tid];
    if (tid == 0) {
        mWS[b * 32 + st] = mtile;
        lWS[b * 32 + st] = mlS[1];
    }

    // ---- PV: ctxPart[d] = sum_s p[s] * memory_fp32[s,d]  (tile is cache-hot) ----
    const int sg = tid >> 7;       // 4 groups of 32 s-rows
    const int dc = tid & 127;      // float4 column
    const float4* m4 = (const float4*)(memory + ((size_t)b * SS + s0) * 512);
    float4 a4 = {0.f, 0.f, 0.f, 0.f};
#pragma unroll 8
    for (int i = 0; i < 32; ++i) {
        int s = sg * 32 + i;
        float w = pS[s];
        float4 f = m4[(size_t)s * 128 + dc];
        a4.x += w * f.x; a4.y += w * f.y; a4.z += w * f.z; a4.w += w * f.w;
    }
    red4[sg * 128 + dc] = a4;      // aliases tileB0 (GEMM reads complete)
    __syncthreads();
    if (tid < 128) {
        float4 r0 = red4[tid], r1 = red4[128 + tid], r2 = red4[256 + tid], r3 = red4[384 + tid];
        float4 o;
        o.x = r0.x + r1.x + r2.x + r3.x;
        o.y = r0.y + r1.y + r2.y + r3.y;
        o.z = r0.z + r1.z + r2.z + r3.z;
        o.w = r0.w + r1.w + r2.w + r3.w;
        ((float4*)(ctxPart + ((size_t)(b * 32 + st)) * 512))[tid] = o;
    }
}

// ---------------- combine: cross-tile softmax merge -> attn (in place), ctx --------
__global__ __launch_bounds__(512)
void combine_kernel(const float* __restrict__ mWS,
                    const float* __restrict__ lWS,
                    const float* __restrict__ ctxPart,
                    float* __restrict__ ctx,
                    float* __restrict__ attn) {
    const int b = blockIdx.x;
    const int tid = threadIdx.x;   // 512
    __shared__ float scaleS[32];
    __shared__ float gS[2];

    if (tid < 64) {
        float mv = (tid < 32) ? mWS[b * 32 + tid] : -INFINITY;
#pragma unroll
        for (int off = 32; off >= 1; off >>= 1) mv = fmaxf(mv, __shfl_xor(mv, off, 64));
        if (tid == 0) gS[0] = mv;
    }
    __syncthreads();
    const float gmax = gS[0];
    if (tid < 64) {
        float sc = 0.f, lv = 0.f;
        if (tid < 32) {
            sc = __expf(mWS[b * 32 + tid] - gmax);
            scaleS[tid] = sc;
            lv = lWS[b * 32 + tid] * sc;
        }
#pragma unroll
        for (int off = 32; off >= 1; off >>= 1) lv += __shfl_xor(lv, off, 64);
        if (tid == 0) gS[1] = lv;
    }
    __syncthreads();
    const float inv = 1.0f / gS[1];

    // ctx[b, d] = sum_st ctxPart[st, d] * scale[st] * inv   (no atomics)
    float facc = 0.f;
#pragma unroll 8
    for (int st = 0; st < 32; ++st)
        facc += ctxPart[((size_t)(b * 32 + st)) * 512 + tid] * scaleS[st];
    ctx[b * 512 + tid] = facc * inv;

    // attn[b, s] holds unnormalized p -> rescale in place
#pragma unroll
    for (int j = 0; j < 8; ++j) {
        size_t idx = (size_t)b * SS + j * 512 + tid;
        attn[idx] = attn[idx] * scaleS[(j * 512 + tid) >> 7] * inv;
    }
}

// ---------------- launch ----------------
extern "C" void kernel_launch(void* const* d_in, const int* in_sizes, int n_in,
                              void* d_out, int out_size, void* d_ws, size_t ws_size,
                              hipStream_t stream) {
    (void)in_sizes; (void)n_in; (void)out_size; (void)ws_size;
    const float* hidden   = (const float*)d_in[0];
    const float* memory   = (const float*)d_in[1];
    const unsigned char* mem_pad = (const unsigned char*)d_in[2];
    const float* coverage = (const float*)d_in[3];
    const float* Wh       = (const float*)d_in[4];
    const float* Wm       = (const float*)d_in[5];
    const float* Wc       = (const float*)d_in[6];
    const float* v        = (const float*)d_in[7];

    char* ws = (char*)d_ws;
    short* Wt      = (short*)ws;                       // 512 KB
    float* h       = (float*)(ws + 512 * 1024);        // 64 KB
    float* mWS     = (float*)(ws + 576 * 1024);        // 4 KB (32 x 32)
    float* lWS     = (float*)(ws + 580 * 1024);        // 4 KB
    float* ctxPart = (float*)(ws + 584 * 1024);        // 2 MB (32 x 32 x 512)
    // total ws use: 2.57 MB  (<= 2.625 MB proven envelope)

    float* ctx  = (float*)d_out;
    float* attn = (float*)d_out + BB * 512;            // doubles as p buffer

    hipMemsetAsync(h, 0, BB * 512 * sizeof(float), stream);
    prep_wt_kernel<<<dim3(16, 16), dim3(256), 0, stream>>>(Wm, Wt);
    prep_h_kernel<<<dim3(32, 2, 4), dim3(256), 0, stream>>>(hidden, Wh, h);
    fused_kernel<<<dim3(BB * 32), dim3(512), 0, stream>>>(
        memory, coverage, mem_pad, Wt, h, Wc, v, attn, mWS, lWS, ctxPart);
    combine_kernel<<<dim3(BB), dim3(512), 0, stream>>>(mWS, lWS, ctxPart, ctx, attn);
}